// Round 4
// baseline (2622.753 us; speedup 1.0000x reference)
//
#include <hip/hip_runtime.h>

#define BATCH 2048
#define FEAT  768
#define NIND  1024
#define NCLS  16

typedef unsigned short u16;
typedef __attribute__((ext_vector_type(8))) __bf16 bf16x8;
typedef __attribute__((ext_vector_type(4))) float f32x4;

static __device__ __forceinline__ unsigned f2bf(float f) {
  unsigned u = __float_as_uint(f);
  unsigned r = ((u >> 16) & 1u) + 0x7FFFu;
  return (u + r) >> 16;                       // RNE bf16 in low 16 bits
}

// K1: phi = sqrt(2/N)*cos(2*(x@W+b)); writes phi [B][N] f32, phiB [B][N] bf16,
//     phiT [N][B] f32, phiTB [N][B] bf16
__global__ __launch_bounds__(256) void phi_kernel(
    const float* __restrict__ x, const float* __restrict__ rw,
    const float* __restrict__ rb, float* __restrict__ phi,
    u16* __restrict__ phiB, float* __restrict__ phiT, u16* __restrict__ phiTB)
{
  __shared__ float xs[64][17];
  __shared__ float wsh[16][68];
  __shared__ float ts[64][65];
  const int b0 = blockIdx.x * 64, i0 = blockIdx.y * 64;
  const int tid = threadIdx.x;
  const int tr = tid >> 4, tc = tid & 15;
  float acc[4][4] = {};
  for (int k0 = 0; k0 < FEAT; k0 += 16) {
    {
      int bb = tid >> 2, kk = (tid & 3) << 2;
      float4 v = *(const float4*)(x + (size_t)(b0 + bb) * FEAT + k0 + kk);
      xs[bb][kk] = v.x; xs[bb][kk+1] = v.y; xs[bb][kk+2] = v.z; xs[bb][kk+3] = v.w;
      int k2 = tid >> 4, ii = (tid & 15) << 2;
      *(float4*)(&wsh[k2][ii]) = *(const float4*)(rw + (size_t)(k0 + k2) * NIND + i0 + ii);
    }
    __syncthreads();
    #pragma unroll
    for (int q = 0; q < 16; ++q) {
      float a[4];
      #pragma unroll
      for (int r = 0; r < 4; ++r) a[r] = xs[tr*4+r][q];
      float4 b4 = *(const float4*)(&wsh[q][tc*4]);
      float bv[4] = {b4.x, b4.y, b4.z, b4.w};
      #pragma unroll
      for (int r = 0; r < 4; ++r)
        #pragma unroll
        for (int c = 0; c < 4; ++c) acc[r][c] += a[r] * bv[c];
    }
    __syncthreads();
  }
  const float SC = 0.04419417382415922f;   // sqrt(2/1024)
  float4 rb4 = *(const float4*)(rb + i0 + tc*4);
  float rbl[4] = {rb4.x, rb4.y, rb4.z, rb4.w};
  #pragma unroll
  for (int r = 0; r < 4; ++r) {
    float vals[4];
    #pragma unroll
    for (int c = 0; c < 4; ++c) {
      float pr = 2.0f * (acc[r][c] + rbl[c]);
      vals[c] = SC * cosf(pr);
      ts[tr*4+r][tc*4+c] = vals[c];
    }
    float4 o = make_float4(vals[0], vals[1], vals[2], vals[3]);
    *(float4*)(phi + (size_t)(b0 + tr*4 + r) * NIND + i0 + tc*4) = o;
    uint2 ob;
    ob.x = (f2bf(o.x) & 0xFFFFu) | (f2bf(o.y) << 16);
    ob.y = (f2bf(o.z) & 0xFFFFu) | (f2bf(o.w) << 16);
    *(uint2*)(phiB + (size_t)(b0 + tr*4 + r) * NIND + i0 + tc*4) = ob;
  }
  __syncthreads();
  #pragma unroll
  for (int rep = 0; rep < 4; ++rep) {
    int ii = tr*4 + rep;
    int bb2 = tc*4;
    float4 o = make_float4(ts[bb2][ii], ts[bb2+1][ii], ts[bb2+2][ii], ts[bb2+3][ii]);
    *(float4*)(phiT + (size_t)(i0 + ii) * BATCH + b0 + bb2) = o;
    uint2 ob;
    ob.x = (f2bf(o.x) & 0xFFFFu) | (f2bf(o.y) << 16);
    ob.y = (f2bf(o.z) & 0xFFFFu) | (f2bf(o.w) << 16);
    *(uint2*)(phiTB + (size_t)(i0 + ii) * BATCH + b0 + bb2) = ob;
  }
}

// K2 v2: tiled logits GEMM (64 b x 16 k per block) + in-block softmax -> wmat
__global__ __launch_bounds__(256) void logits_kernel(
    const float* __restrict__ phi, const float* __restrict__ bw,
    const float* __restrict__ bbias, float* __restrict__ out,
    float* __restrict__ wmat)
{
  __shared__ float ph[64][132];
  __shared__ float bwl[16][132];
  __shared__ float lg[64][17];
  const int b0 = blockIdx.x * 64;
  const int tid = threadIdx.x;
  const int bl = tid & 63, kq = tid >> 6;      // thread owns b=bl, k = kq*4..kq*4+3
  float acc[4] = {};
  for (int kb = 0; kb < NIND; kb += 128) {
    #pragma unroll
    for (int i = 0; i < 8; ++i) {
      int f = i * 256 + tid;                   // 2048 float4-slots
      int row = f >> 5, c4 = (f & 31) << 2;
      *(float4*)(&ph[row][c4]) = *(const float4*)(phi + (size_t)(b0 + row) * NIND + kb + c4);
    }
    #pragma unroll
    for (int i = 0; i < 2; ++i) {
      int f = i * 256 + tid;                   // 512 float4-slots
      int row = f >> 5, c4 = (f & 31) << 2;
      *(float4*)(&bwl[row][c4]) = *(const float4*)(bw + (size_t)row * NIND + kb + c4);
    }
    __syncthreads();
    #pragma unroll 8
    for (int q = 0; q < 128; q += 4) {
      float4 a = *(const float4*)(&ph[bl][q]);
      #pragma unroll
      for (int j = 0; j < 4; ++j) {
        float4 b4 = *(const float4*)(&bwl[kq*4+j][q]);
        acc[j] += a.x*b4.x + a.y*b4.y + a.z*b4.z + a.w*b4.w;
      }
    }
    __syncthreads();
  }
  #pragma unroll
  for (int j = 0; j < 4; ++j) {
    float v = acc[j] + bbias[kq*4+j];
    lg[bl][kq*4+j] = v;
    out[(size_t)(b0 + bl) * NCLS + kq*4 + j] = v;
  }
  __syncthreads();
  if (tid < 64) {
    float mx = -1e30f;
    #pragma unroll
    for (int k = 0; k < 16; ++k) mx = fmaxf(mx, lg[tid][k]);
    float s = 0.f, ex[16];
    #pragma unroll
    for (int k = 0; k < 16; ++k) { ex[k] = expf(lg[tid][k] - mx); s += ex[k]; }
    float inv = 1.0f / s;
    #pragma unroll
    for (int k = 0; k < 16; ++k) {
      float p = ex[k] * inv;
      wmat[(size_t)k * BATCH + b0 + tid] = p * (1.0f - p);
    }
  }
}

// K2b: phiW[k][i][b] = bf16(wmat[k][b] * phiT[i][b])
__global__ __launch_bounds__(256) void scalew_kernel(
    const float* __restrict__ phiT, const float* __restrict__ wmat,
    u16* __restrict__ phiW)
{
  const int k = blockIdx.y;
  size_t flat = ((size_t)blockIdx.x * 256 + threadIdx.x) * 8;
  int i = (int)(flat >> 11), b = (int)(flat & 2047);
  float4 p0 = *(const float4*)(phiT + (size_t)i * BATCH + b);
  float4 p1 = *(const float4*)(phiT + (size_t)i * BATCH + b + 4);
  float4 w0 = *(const float4*)(wmat + (size_t)k * BATCH + b);
  float4 w1 = *(const float4*)(wmat + (size_t)k * BATCH + b + 4);
  uint4 o;
  o.x = (f2bf(p0.x*w0.x) & 0xFFFFu) | (f2bf(p0.y*w0.y) << 16);
  o.y = (f2bf(p0.z*w0.z) & 0xFFFFu) | (f2bf(p0.w*w0.w) << 16);
  o.z = (f2bf(p1.x*w1.x) & 0xFFFFu) | (f2bf(p1.y*w1.y) << 16);
  o.w = (f2bf(p1.z*w1.z) & 0xFFFFu) | (f2bf(p1.w*w1.w) << 16);
  *(uint4*)(phiW + (size_t)k * NIND * BATCH + flat) = o;
}

// K3: MFMA bf16 gram. 128x128 tile per (tile-pair, class), BK=64, XOR-swizzled LDS.
// prec assumed symmetric (ridge*I in this problem): read once per pair.
__global__ __launch_bounds__(256) void gram_kernel(
    const u16* __restrict__ phiW, const u16* __restrict__ phiTB,
    const float* __restrict__ prec, float* __restrict__ P)
{
  __shared__ u16 Als[128 * 64];
  __shared__ u16 Bls[128 * 64];
  int p = blockIdx.x;                 // 36 lower tile-pairs of 8x8
  int ti = 0;
  while ((ti + 1) * (ti + 2) / 2 <= p) ++ti;
  int tj = p - ti * (ti + 1) / 2;
  const int k = blockIdx.y;
  const int i0 = ti * 128, j0 = tj * 128;
  const int tid = threadIdx.x;
  const int wid = tid >> 6, lane = tid & 63;
  const int wr = wid >> 1, wc = wid & 1;
  const u16* Ag = phiW + (size_t)k * NIND * BATCH + (size_t)i0 * BATCH;
  const u16* Bg = phiTB + (size_t)j0 * BATCH;
  f32x4 acc[4][4];
  #pragma unroll
  for (int m = 0; m < 4; ++m)
    #pragma unroll
    for (int n = 0; n < 4; ++n) acc[m][n] = (f32x4){0.f, 0.f, 0.f, 0.f};
  for (int b0 = 0; b0 < BATCH; b0 += 64) {
    #pragma unroll
    for (int c = 0; c < 4; ++c) {
      int f = c * 256 + tid;
      int row = f >> 3, kc8 = f & 7;
      uint4 va = *(const uint4*)(Ag + (size_t)row * BATCH + b0 + kc8 * 8);
      uint4 vb = *(const uint4*)(Bg + (size_t)row * BATCH + b0 + kc8 * 8);
      int idx = (row * 64 + kc8 * 8) ^ ((row & 7) << 3);
      *(uint4*)(&Als[idx]) = va;
      *(uint4*)(&Bls[idx]) = vb;
    }
    __syncthreads();
    #pragma unroll
    for (int ks = 0; ks < 2; ++ks) {
      bf16x8 af[4], bfr[4];
      #pragma unroll
      for (int m = 0; m < 4; ++m) {
        int row = wr * 64 + m * 16 + (lane & 15);
        int kb = ks * 32 + (lane >> 4) * 8;
        int idx = (row * 64 + kb) ^ ((row & 7) << 3);
        af[m] = *(const bf16x8*)(&Als[idx]);
      }
      #pragma unroll
      for (int n = 0; n < 4; ++n) {
        int row = wc * 64 + n * 16 + (lane & 15);
        int kb = ks * 32 + (lane >> 4) * 8;
        int idx = (row * 64 + kb) ^ ((row & 7) << 3);
        bfr[n] = *(const bf16x8*)(&Bls[idx]);
      }
      #pragma unroll
      for (int m = 0; m < 4; ++m)
        #pragma unroll
        for (int n = 0; n < 4; ++n)
          acc[m][n] = __builtin_amdgcn_mfma_f32_16x16x32_bf16(af[m], bfr[n], acc[m][n], 0, 0, 0);
    }
    __syncthreads();
  }
  const size_t kb2 = (size_t)k * NIND * NIND;
  #pragma unroll
  for (int m = 0; m < 4; ++m) {
    #pragma unroll
    for (int n = 0; n < 4; ++n) {
      #pragma unroll
      for (int r = 0; r < 4; ++r) {
        int gi = i0 + wr * 64 + m * 16 + (lane >> 4) * 4 + r;
        int gj = j0 + wc * 64 + n * 16 + (lane & 15);
        float v = acc[m][n][r];
        size_t idx = kb2 + (size_t)gi * NIND + gj;
        float pr = prec[idx];
        P[idx] = v + pr;
        if (ti != tj) {
          size_t idx2 = kb2 + (size_t)gj * NIND + gi;
          P[idx2] = v + pr;
        }
      }
    }
  }
}

// K4: factor 128x128 diag block + blocked triangular inverse; writes invL and U diag
__global__ __launch_bounds__(1024) void potrf_kernel(
    float* __restrict__ P, float* __restrict__ invL,
    float* __restrict__ Uf32, u16* __restrict__ Ubf16, int it)
{
  __shared__ float D[128][129];
  __shared__ float W[128][132];
  __shared__ float sdiag[128];
  __shared__ float sinv[128];
  __shared__ float Tmp[3][32][33];
  const int k = blockIdx.x, tid = threadIdx.x;
  const size_t base = (size_t)k * NIND * NIND + (size_t)(it * 128) * NIND + it * 128;
  for (int t = tid; t < 128 * 128; t += 1024)
    D[t >> 7][t & 127] = P[base + (size_t)(t >> 7) * NIND + (t & 127)];
  __syncthreads();
  const int row = tid & 127, q = tid >> 7;
  for (int j = 0; j < 127; ++j) {
    if (row > j) {
      float invd = 1.0f / D[j][j];
      float lr = D[row][j] * invd;
      for (int c = j + 1 + q; c <= row; c += 8)
        D[row][c] -= lr * D[c][j];
    }
    __syncthreads();
  }
  if (tid < 128) {
    float d = D[tid][tid];
    float s = sqrtf(d);
    sdiag[tid] = s;
    sinv[tid] = 1.0f / s;
  }
  __syncthreads();
  for (int t = tid; t < 128 * 128; t += 1024) {
    int r = t >> 7, c = t & 127;
    if (r > c) D[r][c] *= sinv[c];
    else if (r == c) D[r][c] = sdiag[c];
  }
  __syncthreads();
  if (tid < 128) {
    int blk = tid >> 5, c = tid & 31, b0 = blk * 32;
    for (int r = 0; r < 32; ++r) {
      if (r < c) { W[b0 + r][b0 + c] = 0.f; }
      else {
        float s = 0.f;
        for (int j = c; j < r; ++j) s += D[b0 + r][b0 + j] * W[b0 + j][b0 + c];
        float v = ((r == c) ? 1.0f : 0.0f) - s;
        W[b0 + r][b0 + c] = v * sinv[b0 + r];
      }
    }
  }
  __syncthreads();
  for (int d = 1; d <= 3; ++d) {
    int nb = 4 - d;
    for (int t = tid; t < nb * 1024; t += 1024) {
      int bi = t >> 10, rc = t & 1023, r = rc >> 5, c = rc & 31;
      int J = bi, I = J + d;
      float s = 0.f;
      for (int K = J; K < I; ++K)
        #pragma unroll 8
        for (int j = 0; j < 32; ++j)
          s += D[I*32 + r][K*32 + j] * W[K*32 + j][J*32 + c];
      Tmp[bi][r][c] = s;
    }
    __syncthreads();
    for (int t = tid; t < nb * 1024; t += 1024) {
      int bi = t >> 10, rc = t & 1023, r = rc >> 5, c = rc & 31;
      int J = bi, I = J + d;
      float s = 0.f;
      for (int j = 0; j <= r; ++j)
        s += W[I*32 + r][I*32 + j] * Tmp[bi][j][c];
      W[I*32 + r][J*32 + c] = -s;
    }
    __syncthreads();
  }
  const size_t ub = (size_t)k * NIND * NIND + (size_t)(it * 128) * NIND + it * 128;
  for (int t = tid; t < 128 * 128; t += 1024) {
    int r = t >> 7, c = t & 127;
    float v = (c <= r) ? W[r][c] : 0.f;
    invL[((size_t)k * 8 + it) * 16384 + t] = v;
    Uf32[ub + (size_t)r * NIND + c] = v;
    Ubf16[ub + (size_t)r * NIND + c] = (u16)f2bf(v);
  }
}

// K5: panel trsm: L21 = A21 * invL11^T
__global__ __launch_bounds__(256) void trsm_kernel(
    float* __restrict__ P, const float* __restrict__ invL, int it)
{
  __shared__ float As[64][17];
  __shared__ float Ls[128][17];
  const int k = blockIdx.y;
  const int r0 = (it + 1) * 128 + blockIdx.x * 64;
  const int jb = it * 128;
  const int tid = threadIdx.x, tr = tid >> 4, tc = tid & 15;
  const size_t pb = (size_t)k * NIND * NIND;
  const float* invb = invL + ((size_t)k * 8 + it) * 16384;
  float acc[4][8] = {};
  for (int j0 = 0; j0 < 128; j0 += 16) {
    {
      int rr = tid >> 2, jj = (tid & 3) << 2;
      float4 v = *(const float4*)(P + pb + (size_t)(r0 + rr) * NIND + jb + j0 + jj);
      As[rr][jj] = v.x; As[rr][jj+1] = v.y; As[rr][jj+2] = v.z; As[rr][jj+3] = v.w;
      #pragma unroll
      for (int t = 0; t < 2; ++t) {
        int f = tid + t * 256;
        int r2 = f >> 2, j2 = (f & 3) << 2;
        float4 u = *(const float4*)(invb + (size_t)r2 * 128 + j0 + j2);
        Ls[r2][j2] = u.x; Ls[r2][j2+1] = u.y; Ls[r2][j2+2] = u.z; Ls[r2][j2+3] = u.w;
      }
    }
    __syncthreads();
    #pragma unroll
    for (int qq = 0; qq < 16; ++qq) {
      float a[4];
      #pragma unroll
      for (int r = 0; r < 4; ++r) a[r] = As[tr*4+r][qq];
      #pragma unroll
      for (int c = 0; c < 8; ++c) {
        float lv = Ls[tc*8+c][qq];
        #pragma unroll
        for (int r = 0; r < 4; ++r) acc[r][c] += a[r] * lv;
      }
    }
    __syncthreads();
  }
  #pragma unroll
  for (int r = 0; r < 4; ++r) {
    #pragma unroll
    for (int c0 = 0; c0 < 8; c0 += 4) {
      float4 o = make_float4(acc[r][c0], acc[r][c0+1], acc[r][c0+2], acc[r][c0+3]);
      *(float4*)(P + pb + (size_t)(r0 + tr*4 + r) * NIND + jb + tc*8 + c0) = o;
    }
  }
}

// K6: trailing update A22 -= L21 L21^T
__global__ __launch_bounds__(256) void syrk_kernel(float* __restrict__ P, int it)
{
  __shared__ float Pa[64][17];
  __shared__ float Pb[64][17];
  int p = blockIdx.x;
  int a = (int)((sqrtf(8.f * p + 1.f) - 1.f) * 0.5f);
  while ((a + 1) * (a + 2) / 2 <= p) ++a;
  while (a * (a + 1) / 2 > p) --a;
  int b = p - a * (a + 1) / 2;
  const int tbase = (it + 1) * 2;
  const int r0 = (tbase + a) * 64, c0 = (tbase + b) * 64;
  const int jb = it * 128;
  const int k = blockIdx.y;
  const size_t pb = (size_t)k * NIND * NIND;
  const int tid = threadIdx.x, tr = tid >> 4, tc = tid & 15;
  float acc[4][4] = {};
  for (int j0 = 0; j0 < 128; j0 += 16) {
    int rr = tid >> 2, jj = (tid & 3) << 2;
    float4 v = *(const float4*)(P + pb + (size_t)(r0 + rr) * NIND + jb + j0 + jj);
    Pa[rr][jj] = v.x; Pa[rr][jj+1] = v.y; Pa[rr][jj+2] = v.z; Pa[rr][jj+3] = v.w;
    float4 u = *(const float4*)(P + pb + (size_t)(c0 + rr) * NIND + jb + j0 + jj);
    Pb[rr][jj] = u.x; Pb[rr][jj+1] = u.y; Pb[rr][jj+2] = u.z; Pb[rr][jj+3] = u.w;
    __syncthreads();
    #pragma unroll
    for (int qq = 0; qq < 16; ++qq) {
      float av[4], bv[4];
      #pragma unroll
      for (int r = 0; r < 4; ++r) av[r] = Pa[tr*4+r][qq];
      #pragma unroll
      for (int c = 0; c < 4; ++c) bv[c] = Pb[tc*4+c][qq];
      #pragma unroll
      for (int r = 0; r < 4; ++r)
        #pragma unroll
        for (int c = 0; c < 4; ++c) acc[r][c] += av[r] * bv[c];
    }
    __syncthreads();
  }
  #pragma unroll
  for (int r = 0; r < 4; ++r) {
    float* dst = P + pb + (size_t)(r0 + tr*4 + r) * NIND + c0 + tc*4;
    float4 cur = *(float4*)dst;
    cur.x -= acc[r][0]; cur.y -= acc[r][1]; cur.z -= acc[r][2]; cur.w -= acc[r][3];
    *(float4*)dst = cur;
  }
}

// K8: triangular-inverse level d: U_IJ = -invL_II * (sum_{K=J}^{I-1} L_IK U_KJ), I=J+d
__global__ __launch_bounds__(256) void triinv_kernel(
    const float* __restrict__ P, const float* __restrict__ invL,
    float* __restrict__ Uf32, u16* __restrict__ Ubf16, int d)
{
  __shared__ float As[128][17];
  __shared__ float Bs[16][129];
  __shared__ float Ts[128][129];
  const int J = blockIdx.x, I = J + d, k = blockIdx.y;
  const int tid = threadIdx.x, tr = tid >> 4, tc = tid & 15;
  const size_t pb = (size_t)k * NIND * NIND;
  const size_t ubase = (size_t)k * NIND * NIND;
  float acc[8][8] = {};
  // stage 1: T = sum L_IK U_KJ, K-dim = d*128 (absolute cols J*128 .. I*128)
  for (int kb = 0; kb < d * 128; kb += 16) {
    #pragma unroll
    for (int t = 0; t < 2; ++t) {
      int f = t * 256 + tid;               // 512 float4-slots = 128x16
      int r2 = f >> 2, q4 = (f & 3) << 2;
      *(float4*)(&As[r2][q4]) =
          *(const float4*)(P + pb + (size_t)(I*128 + r2) * NIND + J*128 + kb + q4);
    }
    #pragma unroll
    for (int t = 0; t < 2; ++t) {
      int f = t * 256 + tid;               // 512 float4-slots = 16x128
      int q2 = f >> 5, c4 = (f & 31) << 2;
      *(float4*)(&Bs[q2][c4]) =
          *(const float4*)(Uf32 + ubase + (size_t)(J*128 + kb + q2) * NIND + J*128 + c4);
    }
    __syncthreads();
    #pragma unroll
    for (int q = 0; q < 16; ++q) {
      float a[8], b[8];
      #pragma unroll
      for (int r = 0; r < 8; ++r) a[r] = As[tr*8+r][q];
      #pragma unroll
      for (int c = 0; c < 8; ++c) b[c] = Bs[q][tc*8+c];
      #pragma unroll
      for (int r = 0; r < 8; ++r)
        #pragma unroll
        for (int c = 0; c < 8; ++c) acc[r][c] += a[r] * b[c];
    }
    __syncthreads();
  }
  #pragma unroll
  for (int r = 0; r < 8; ++r)
    #pragma unroll
    for (int c = 0; c < 8; ++c) Ts[tr*8+r][tc*8+c] = acc[r][c];
  __syncthreads();
  // stage 2: U_IJ = -invL_II * T
  const float* invb = invL + ((size_t)k * 8 + I) * 16384;
  float acc2[8][8] = {};
  for (int kb = 0; kb < 128; kb += 16) {
    #pragma unroll
    for (int t = 0; t < 2; ++t) {
      int f = t * 256 + tid;
      int r2 = f >> 2, q4 = (f & 3) << 2;
      *(float4*)(&As[r2][q4]) = *(const float4*)(invb + (size_t)r2 * 128 + kb + q4);
    }
    __syncthreads();
    #pragma unroll
    for (int q = 0; q < 16; ++q) {
      float a[8], b[8];
      #pragma unroll
      for (int r = 0; r < 8; ++r) a[r] = As[tr*8+r][q];
      #pragma unroll
      for (int c = 0; c < 8; ++c) b[c] = Ts[kb+q][tc*8+c];
      #pragma unroll
      for (int r = 0; r < 8; ++r)
        #pragma unroll
        for (int c = 0; c < 8; ++c) acc2[r][c] += a[r] * b[c];
    }
    __syncthreads();
  }
  #pragma unroll
  for (int r = 0; r < 8; ++r) {
    #pragma unroll
    for (int c = 0; c < 8; ++c) {
      float v = -acc2[r][c];
      size_t idx = ubase + (size_t)(I*128 + tr*8 + r) * NIND + J*128 + tc*8 + c;
      Uf32[idx] = v;
      Ubf16[idx] = (u16)f2bf(v);
    }
  }
}

// K9: Y = U * phi^T (triangular K-limit), fused column square-sums -> partial[It][k][b]
__global__ __launch_bounds__(256) void ygemm_kernel(
    const u16* __restrict__ Ubf16, const u16* __restrict__ phiB,
    float* __restrict__ partial)
{
  __shared__ u16 Als[128 * 64];
  __shared__ u16 Bls[128 * 64];
  __shared__ float sq_lds[128][9];
  const int b0 = blockIdx.x * 128;
  const int It = blockIdx.y;
  const int k = blockIdx.z;
  const int tid = threadIdx.x;
  const int wid = tid >> 6, lane = tid & 63;
  const int wr = wid >> 1, wc = wid & 1;
  const u16* Ag = Ubf16 + (size_t)k * NIND * NIND + (size_t)(It * 128) * NIND;
  const u16* Bg = phiB + (size_t)b0 * NIND;
  f32x4 acc[4][4];
  #pragma unroll
  for (int m = 0; m < 4; ++m)
    #pragma unroll
    for (int n = 0; n < 4; ++n) acc[m][n] = (f32x4){0.f, 0.f, 0.f, 0.f};
  const int Kmax = (It + 1) * 128;
  for (int j0 = 0; j0 < Kmax; j0 += 64) {
    #pragma unroll
    for (int c = 0; c < 4; ++c) {
      int f = c * 256 + tid;
      int row = f >> 3, kc8 = f & 7;
      uint4 va = *(const uint4*)(Ag + (size_t)row * NIND + j0 + kc8 * 8);
      uint4 vb = *(const uint4*)(Bg + (size_t)row * NIND + j0 + kc8 * 8);
      int idx = (row * 64 + kc8 * 8) ^ ((row & 7) << 3);
      *(uint4*)(&Als[idx]) = va;
      *(uint4*)(&Bls[idx]) = vb;
    }
    __syncthreads();
    #pragma unroll
    for (int ks = 0; ks < 2; ++ks) {
      bf16x8 af[4], bfr[4];
      #pragma unroll
      for (int m = 0; m < 4; ++m) {
        int row = wr * 64 + m * 16 + (lane & 15);
        int kb = ks * 32 + (lane >> 4) * 8;
        int idx = (row * 64 + kb) ^ ((row & 7) << 3);
        af[m] = *(const bf16x8*)(&Als[idx]);
      }
      #pragma unroll
      for (int n = 0; n < 4; ++n) {
        int row = wc * 64 + n * 16 + (lane & 15);
        int kb = ks * 32 + (lane >> 4) * 8;
        int idx = (row * 64 + kb) ^ ((row & 7) << 3);
        bfr[n] = *(const bf16x8*)(&Bls[idx]);
      }
      #pragma unroll
      for (int m = 0; m < 4; ++m)
        #pragma unroll
        for (int n = 0; n < 4; ++n)
          acc[m][n] = __builtin_amdgcn_mfma_f32_16x16x32_bf16(af[m], bfr[n], acc[m][n], 0, 0, 0);
    }
    __syncthreads();
  }
  // column (b) square-sums: contributors per column = wr(2) x lane>>4(4)
  #pragma unroll
  for (int n = 0; n < 4; ++n) {
    float s = 0.f;
    #pragma unroll
    for (int m = 0; m < 4; ++m)
      #pragma unroll
      for (int r = 0; r < 4; ++r) { float v = acc[m][n][r]; s += v * v; }
    int col = wc * 64 + n * 16 + (lane & 15);
    sq_lds[col][wr * 4 + (lane >> 4)] = (wr == 0 && (lane >> 4) == 0) ? s : s;
    // each (wr, lane>>4) slot unique; write below after zero not needed (all 8 written)
  }
  __syncthreads();
  if (tid < 128) {
    float s = 0.f;
    #pragma unroll
    for (int t = 0; t < 8; ++t) s += sq_lds[tid][t];
    partial[((size_t)It * NCLS + k) * BATCH + b0 + tid] = s;
  }
}

// K10: out variances[b][k] = sum_It partial[It][k][b]
__global__ __launch_bounds__(256) void reduce_kernel(
    const float* __restrict__ partial, float* __restrict__ out)
{
  int t = blockIdx.x * 256 + threadIdx.x;       // 32768
  int k = t >> 11, b = t & 2047;
  float s = 0.f;
  #pragma unroll
  for (int It = 0; It < 8; ++It)
    s += partial[((size_t)It * NCLS + k) * BATCH + b];
  out[(size_t)BATCH * NCLS + (size_t)b * NCLS + k] = s;
}

extern "C" void kernel_launch(void* const* d_in, const int* in_sizes, int n_in,
                              void* d_out, int out_size, void* d_ws, size_t ws_size,
                              hipStream_t stream)
{
  (void)in_sizes; (void)n_in; (void)ws_size;
  const float* x   = (const float*)d_in[0];
  const float* rw  = (const float*)d_in[1];
  const float* rb  = (const float*)d_in[2];
  const float* bw  = (const float*)d_in[3];
  const float* bb  = (const float*)d_in[4];
  const float* prc = (const float*)d_in[5];
  float* out = (float*)d_out;
  char* ws = (char*)d_ws;
  size_t off = 0;
  auto alloc = [&](size_t bytes) -> void* {
    void* p = ws + off;
    off = (off + bytes + 255) & ~(size_t)255;
    return p;
  };
  float* phi   = (float*)alloc((size_t)BATCH * NIND * 4);
  u16*   phiB  = (u16*)  alloc((size_t)BATCH * NIND * 2);
  float* phiT  = (float*)alloc((size_t)NIND * BATCH * 4);
  u16*   phiTB = (u16*)  alloc((size_t)NIND * BATCH * 2);
  float* wmat  = (float*)alloc((size_t)NCLS * BATCH * 4);
  float* P     = (float*)alloc((size_t)NCLS * NIND * NIND * 4);
  float* invL  = (float*)alloc((size_t)NCLS * 8 * 128 * 128 * 4);
  u16*   Ubf16 = (u16*)  alloc((size_t)NCLS * NIND * NIND * 2);
  float* partial = (float*)alloc((size_t)8 * NCLS * BATCH * 4);
  // union: phiW (bf16, 64MB, dead after gram) aliased with Uf32 (f32, 64MB)
  u16*   phiW = (u16*)(ws + off);
  float* Uf32 = (float*)(ws + off);

  hipMemsetAsync(d_out, 0, (size_t)out_size * sizeof(float), stream);
  phi_kernel<<<dim3(BATCH/64, NIND/64), 256, 0, stream>>>(x, rw, rb, phi, phiB, phiT, phiTB);
  logits_kernel<<<dim3(BATCH/64), 256, 0, stream>>>(phi, bw, bb, out, wmat);
  scalew_kernel<<<dim3(1024, NCLS), 256, 0, stream>>>(phiT, wmat, phiW);
  gram_kernel<<<dim3(36, NCLS), 256, 0, stream>>>(phiW, phiTB, prc, P);
  for (int it = 0; it < 8; ++it) {
    potrf_kernel<<<dim3(NCLS), 1024, 0, stream>>>(P, invL, Uf32, Ubf16, it);
    if (it < 7) {
      trsm_kernel<<<dim3((7 - it) * 2, NCLS), 256, 0, stream>>>(P, invL, it);
      int n = 14 - 2 * it;
      syrk_kernel<<<dim3(n * (n + 1) / 2, NCLS), 256, 0, stream>>>(P, it);
    }
  }
  for (int d = 1; d <= 7; ++d)
    triinv_kernel<<<dim3(8 - d, NCLS), 256, 0, stream>>>(P, invL, Uf32, Ubf16, d);
  ygemm_kernel<<<dim3(BATCH/128, 8, NCLS), 256, 0, stream>>>(Ubf16, phiB, partial);
  reduce_kernel<<<dim3(128), 256, 0, stream>>>(partial, out);
}

// Round 5
// 2029.178 us; speedup vs baseline: 1.2925x; 1.2925x over previous
//
#include <hip/hip_runtime.h>

#define BATCH 2048
#define FEAT  768
#define NIND  1024
#define NCLS  16

typedef unsigned short u16;
typedef __attribute__((ext_vector_type(8))) __bf16 bf16x8;
typedef __attribute__((ext_vector_type(4))) float f32x4;

static __device__ __forceinline__ unsigned f2bf(float f) {
  unsigned u = __float_as_uint(f);
  unsigned r = ((u >> 16) & 1u) + 0x7FFFu;
  return (u + r) >> 16;                       // RNE bf16 in low 16 bits
}

// K1: phi = sqrt(2/N)*cos(2*(x@W+b)); writes phi [B][N] f32, phiB [B][N] bf16,
//     phiT [N][B] f32, phiTB [N][B] bf16
__global__ __launch_bounds__(256) void phi_kernel(
    const float* __restrict__ x, const float* __restrict__ rw,
    const float* __restrict__ rb, float* __restrict__ phi,
    u16* __restrict__ phiB, float* __restrict__ phiT, u16* __restrict__ phiTB)
{
  __shared__ float xs[64][17];
  __shared__ float wsh[16][68];
  __shared__ float ts[64][65];
  const int b0 = blockIdx.x * 64, i0 = blockIdx.y * 64;
  const int tid = threadIdx.x;
  const int tr = tid >> 4, tc = tid & 15;
  float acc[4][4] = {};
  for (int k0 = 0; k0 < FEAT; k0 += 16) {
    {
      int bb = tid >> 2, kk = (tid & 3) << 2;
      float4 v = *(const float4*)(x + (size_t)(b0 + bb) * FEAT + k0 + kk);
      xs[bb][kk] = v.x; xs[bb][kk+1] = v.y; xs[bb][kk+2] = v.z; xs[bb][kk+3] = v.w;
      int k2 = tid >> 4, ii = (tid & 15) << 2;
      *(float4*)(&wsh[k2][ii]) = *(const float4*)(rw + (size_t)(k0 + k2) * NIND + i0 + ii);
    }
    __syncthreads();
    #pragma unroll
    for (int q = 0; q < 16; ++q) {
      float a[4];
      #pragma unroll
      for (int r = 0; r < 4; ++r) a[r] = xs[tr*4+r][q];
      float4 b4 = *(const float4*)(&wsh[q][tc*4]);
      float bv[4] = {b4.x, b4.y, b4.z, b4.w};
      #pragma unroll
      for (int r = 0; r < 4; ++r)
        #pragma unroll
        for (int c = 0; c < 4; ++c) acc[r][c] += a[r] * bv[c];
    }
    __syncthreads();
  }
  const float SC = 0.04419417382415922f;   // sqrt(2/1024)
  float4 rb4 = *(const float4*)(rb + i0 + tc*4);
  float rbl[4] = {rb4.x, rb4.y, rb4.z, rb4.w};
  #pragma unroll
  for (int r = 0; r < 4; ++r) {
    float vals[4];
    #pragma unroll
    for (int c = 0; c < 4; ++c) {
      float pr = 2.0f * (acc[r][c] + rbl[c]);
      vals[c] = SC * cosf(pr);
      ts[tr*4+r][tc*4+c] = vals[c];
    }
    float4 o = make_float4(vals[0], vals[1], vals[2], vals[3]);
    *(float4*)(phi + (size_t)(b0 + tr*4 + r) * NIND + i0 + tc*4) = o;
    uint2 ob;
    ob.x = (f2bf(o.x) & 0xFFFFu) | (f2bf(o.y) << 16);
    ob.y = (f2bf(o.z) & 0xFFFFu) | (f2bf(o.w) << 16);
    *(uint2*)(phiB + (size_t)(b0 + tr*4 + r) * NIND + i0 + tc*4) = ob;
  }
  __syncthreads();
  #pragma unroll
  for (int rep = 0; rep < 4; ++rep) {
    int ii = tr*4 + rep;
    int bb2 = tc*4;
    float4 o = make_float4(ts[bb2][ii], ts[bb2+1][ii], ts[bb2+2][ii], ts[bb2+3][ii]);
    *(float4*)(phiT + (size_t)(i0 + ii) * BATCH + b0 + bb2) = o;
    uint2 ob;
    ob.x = (f2bf(o.x) & 0xFFFFu) | (f2bf(o.y) << 16);
    ob.y = (f2bf(o.z) & 0xFFFFu) | (f2bf(o.w) << 16);
    *(uint2*)(phiTB + (size_t)(i0 + ii) * BATCH + b0 + bb2) = ob;
  }
}

// K2: tiled logits GEMM (64 b x 16 k per block) + in-block softmax -> wmat
__global__ __launch_bounds__(256) void logits_kernel(
    const float* __restrict__ phi, const float* __restrict__ bw,
    const float* __restrict__ bbias, float* __restrict__ out,
    float* __restrict__ wmat)
{
  __shared__ float ph[64][132];
  __shared__ float bwl[16][132];
  __shared__ float lg[64][17];
  const int b0 = blockIdx.x * 64;
  const int tid = threadIdx.x;
  const int bl = tid & 63, kq = tid >> 6;
  float acc[4] = {};
  for (int kb = 0; kb < NIND; kb += 128) {
    #pragma unroll
    for (int i = 0; i < 8; ++i) {
      int f = i * 256 + tid;
      int row = f >> 5, c4 = (f & 31) << 2;
      *(float4*)(&ph[row][c4]) = *(const float4*)(phi + (size_t)(b0 + row) * NIND + kb + c4);
    }
    #pragma unroll
    for (int i = 0; i < 2; ++i) {
      int f = i * 256 + tid;
      int row = f >> 5, c4 = (f & 31) << 2;
      *(float4*)(&bwl[row][c4]) = *(const float4*)(bw + (size_t)row * NIND + kb + c4);
    }
    __syncthreads();
    #pragma unroll 8
    for (int q = 0; q < 128; q += 4) {
      float4 a = *(const float4*)(&ph[bl][q]);
      #pragma unroll
      for (int j = 0; j < 4; ++j) {
        float4 b4 = *(const float4*)(&bwl[kq*4+j][q]);
        acc[j] += a.x*b4.x + a.y*b4.y + a.z*b4.z + a.w*b4.w;
      }
    }
    __syncthreads();
  }
  #pragma unroll
  for (int j = 0; j < 4; ++j) {
    float v = acc[j] + bbias[kq*4+j];
    lg[bl][kq*4+j] = v;
    out[(size_t)(b0 + bl) * NCLS + kq*4 + j] = v;
  }
  __syncthreads();
  if (tid < 64) {
    float mx = -1e30f;
    #pragma unroll
    for (int k = 0; k < 16; ++k) mx = fmaxf(mx, lg[tid][k]);
    float s = 0.f, ex[16];
    #pragma unroll
    for (int k = 0; k < 16; ++k) { ex[k] = expf(lg[tid][k] - mx); s += ex[k]; }
    float inv = 1.0f / s;
    #pragma unroll
    for (int k = 0; k < 16; ++k) {
      float p = ex[k] * inv;
      wmat[(size_t)k * BATCH + b0 + tid] = p * (1.0f - p);
    }
  }
}

// K2b: phiW[k][i][b] = bf16(wmat[k][b] * phiT[i][b])
__global__ __launch_bounds__(256) void scalew_kernel(
    const float* __restrict__ phiT, const float* __restrict__ wmat,
    u16* __restrict__ phiW)
{
  const int k = blockIdx.y;
  size_t flat = ((size_t)blockIdx.x * 256 + threadIdx.x) * 8;
  int i = (int)(flat >> 11), b = (int)(flat & 2047);
  float4 p0 = *(const float4*)(phiT + (size_t)i * BATCH + b);
  float4 p1 = *(const float4*)(phiT + (size_t)i * BATCH + b + 4);
  float4 w0 = *(const float4*)(wmat + (size_t)k * BATCH + b);
  float4 w1 = *(const float4*)(wmat + (size_t)k * BATCH + b + 4);
  uint4 o;
  o.x = (f2bf(p0.x*w0.x) & 0xFFFFu) | (f2bf(p0.y*w0.y) << 16);
  o.y = (f2bf(p0.z*w0.z) & 0xFFFFu) | (f2bf(p0.w*w0.w) << 16);
  o.z = (f2bf(p1.x*w1.x) & 0xFFFFu) | (f2bf(p1.y*w1.y) << 16);
  o.w = (f2bf(p1.z*w1.z) & 0xFFFFu) | (f2bf(p1.w*w1.w) << 16);
  *(uint4*)(phiW + (size_t)k * NIND * BATCH + flat) = o;
}

// K3: MFMA bf16 gram. 128x128 tile per (tile-pair, class), BK=64, XOR-swizzled LDS.
__global__ __launch_bounds__(256) void gram_kernel(
    const u16* __restrict__ phiW, const u16* __restrict__ phiTB,
    const float* __restrict__ prec, float* __restrict__ P)
{
  __shared__ u16 Als[128 * 64];
  __shared__ u16 Bls[128 * 64];
  int p = blockIdx.x;
  int ti = 0;
  while ((ti + 1) * (ti + 2) / 2 <= p) ++ti;
  int tj = p - ti * (ti + 1) / 2;
  const int k = blockIdx.y;
  const int i0 = ti * 128, j0 = tj * 128;
  const int tid = threadIdx.x;
  const int wid = tid >> 6, lane = tid & 63;
  const int wr = wid >> 1, wc = wid & 1;
  const u16* Ag = phiW + (size_t)k * NIND * BATCH + (size_t)i0 * BATCH;
  const u16* Bg = phiTB + (size_t)j0 * BATCH;
  f32x4 acc[4][4];
  #pragma unroll
  for (int m = 0; m < 4; ++m)
    #pragma unroll
    for (int n = 0; n < 4; ++n) acc[m][n] = (f32x4){0.f, 0.f, 0.f, 0.f};
  for (int b0 = 0; b0 < BATCH; b0 += 64) {
    #pragma unroll
    for (int c = 0; c < 4; ++c) {
      int f = c * 256 + tid;
      int row = f >> 3, kc8 = f & 7;
      uint4 va = *(const uint4*)(Ag + (size_t)row * BATCH + b0 + kc8 * 8);
      uint4 vb = *(const uint4*)(Bg + (size_t)row * BATCH + b0 + kc8 * 8);
      int idx = (row * 64 + kc8 * 8) ^ ((row & 7) << 3);
      *(uint4*)(&Als[idx]) = va;
      *(uint4*)(&Bls[idx]) = vb;
    }
    __syncthreads();
    #pragma unroll
    for (int ks = 0; ks < 2; ++ks) {
      bf16x8 af[4], bfr[4];
      #pragma unroll
      for (int m = 0; m < 4; ++m) {
        int row = wr * 64 + m * 16 + (lane & 15);
        int kb = ks * 32 + (lane >> 4) * 8;
        int idx = (row * 64 + kb) ^ ((row & 7) << 3);
        af[m] = *(const bf16x8*)(&Als[idx]);
      }
      #pragma unroll
      for (int n = 0; n < 4; ++n) {
        int row = wc * 64 + n * 16 + (lane & 15);
        int kb = ks * 32 + (lane >> 4) * 8;
        int idx = (row * 64 + kb) ^ ((row & 7) << 3);
        bfr[n] = *(const bf16x8*)(&Bls[idx]);
      }
      #pragma unroll
      for (int m = 0; m < 4; ++m)
        #pragma unroll
        for (int n = 0; n < 4; ++n)
          acc[m][n] = __builtin_amdgcn_mfma_f32_16x16x32_bf16(af[m], bfr[n], acc[m][n], 0, 0, 0);
    }
    __syncthreads();
  }
  const size_t kb2 = (size_t)k * NIND * NIND;
  #pragma unroll
  for (int m = 0; m < 4; ++m) {
    #pragma unroll
    for (int n = 0; n < 4; ++n) {
      #pragma unroll
      for (int r = 0; r < 4; ++r) {
        int gi = i0 + wr * 64 + m * 16 + (lane >> 4) * 4 + r;
        int gj = j0 + wc * 64 + n * 16 + (lane & 15);
        float v = acc[m][n][r];
        size_t idx = kb2 + (size_t)gi * NIND + gj;
        float pr = prec[idx];
        P[idx] = v + pr;
        if (ti != tj) {
          size_t idx2 = kb2 + (size_t)gj * NIND + gi;
          P[idx2] = v + pr;
        }
      }
    }
  }
}

// K4: factor 128x128 diag block + blocked triangular inverse; writes invL and U diag
__global__ __launch_bounds__(1024) void potrf_kernel(
    float* __restrict__ P, float* __restrict__ invL,
    float* __restrict__ Uf32, u16* __restrict__ Ubf16, int it)
{
  __shared__ float D[128][129];
  __shared__ float W[128][132];
  __shared__ float sdiag[128];
  __shared__ float sinv[128];
  __shared__ float Tmp[3][32][33];
  const int k = blockIdx.x, tid = threadIdx.x;
  const size_t base = (size_t)k * NIND * NIND + (size_t)(it * 128) * NIND + it * 128;
  for (int t = tid; t < 128 * 128; t += 1024)
    D[t >> 7][t & 127] = P[base + (size_t)(t >> 7) * NIND + (t & 127)];
  __syncthreads();
  const int row = tid & 127, q = tid >> 7;
  for (int j = 0; j < 127; ++j) {
    if (row > j) {
      float invd = 1.0f / D[j][j];
      float lr = D[row][j] * invd;
      for (int c = j + 1 + q; c <= row; c += 8)
        D[row][c] -= lr * D[c][j];
    }
    __syncthreads();
  }
  if (tid < 128) {
    float d = D[tid][tid];
    float s = sqrtf(d);
    sdiag[tid] = s;
    sinv[tid] = 1.0f / s;
  }
  __syncthreads();
  for (int t = tid; t < 128 * 128; t += 1024) {
    int r = t >> 7, c = t & 127;
    if (r > c) D[r][c] *= sinv[c];
    else if (r == c) D[r][c] = sdiag[c];
  }
  __syncthreads();
  if (tid < 128) {
    int blk = tid >> 5, c = tid & 31, b0 = blk * 32;
    for (int r = 0; r < 32; ++r) {
      if (r < c) { W[b0 + r][b0 + c] = 0.f; }
      else {
        float s = 0.f;
        for (int j = c; j < r; ++j) s += D[b0 + r][b0 + j] * W[b0 + j][b0 + c];
        float v = ((r == c) ? 1.0f : 0.0f) - s;
        W[b0 + r][b0 + c] = v * sinv[b0 + r];
      }
    }
  }
  __syncthreads();
  for (int d = 1; d <= 3; ++d) {
    int nb = 4 - d;
    for (int t = tid; t < nb * 1024; t += 1024) {
      int bi = t >> 10, rc = t & 1023, r = rc >> 5, c = rc & 31;
      int J = bi, I = J + d;
      float s = 0.f;
      for (int K = J; K < I; ++K)
        #pragma unroll 8
        for (int j = 0; j < 32; ++j)
          s += D[I*32 + r][K*32 + j] * W[K*32 + j][J*32 + c];
      Tmp[bi][r][c] = s;
    }
    __syncthreads();
    for (int t = tid; t < nb * 1024; t += 1024) {
      int bi = t >> 10, rc = t & 1023, r = rc >> 5, c = rc & 31;
      int J = bi, I = J + d;
      float s = 0.f;
      for (int j = 0; j <= r; ++j)
        s += W[I*32 + r][I*32 + j] * Tmp[bi][j][c];
      W[I*32 + r][J*32 + c] = -s;
    }
    __syncthreads();
  }
  const size_t ub = (size_t)k * NIND * NIND + (size_t)(it * 128) * NIND + it * 128;
  for (int t = tid; t < 128 * 128; t += 1024) {
    int r = t >> 7, c = t & 127;
    float v = (c <= r) ? W[r][c] : 0.f;
    invL[((size_t)k * 8 + it) * 16384 + t] = v;
    Uf32[ub + (size_t)r * NIND + c] = v;
    Ubf16[ub + (size_t)r * NIND + c] = (u16)f2bf(v);
  }
}

// K5: panel trsm: L21 = A21 * invL11^T
__global__ __launch_bounds__(256) void trsm_kernel(
    float* __restrict__ P, const float* __restrict__ invL, int it)
{
  __shared__ float As[64][17];
  __shared__ float Ls[128][17];
  const int k = blockIdx.y;
  const int r0 = (it + 1) * 128 + blockIdx.x * 64;
  const int jb = it * 128;
  const int tid = threadIdx.x, tr = tid >> 4, tc = tid & 15;
  const size_t pb = (size_t)k * NIND * NIND;
  const float* invb = invL + ((size_t)k * 8 + it) * 16384;
  float acc[4][8] = {};
  for (int j0 = 0; j0 < 128; j0 += 16) {
    {
      int rr = tid >> 2, jj = (tid & 3) << 2;
      float4 v = *(const float4*)(P + pb + (size_t)(r0 + rr) * NIND + jb + j0 + jj);
      As[rr][jj] = v.x; As[rr][jj+1] = v.y; As[rr][jj+2] = v.z; As[rr][jj+3] = v.w;
      #pragma unroll
      for (int t = 0; t < 2; ++t) {
        int f = tid + t * 256;
        int r2 = f >> 2, j2 = (f & 3) << 2;
        float4 u = *(const float4*)(invb + (size_t)r2 * 128 + j0 + j2);
        Ls[r2][j2] = u.x; Ls[r2][j2+1] = u.y; Ls[r2][j2+2] = u.z; Ls[r2][j2+3] = u.w;
      }
    }
    __syncthreads();
    #pragma unroll
    for (int qq = 0; qq < 16; ++qq) {
      float a[4];
      #pragma unroll
      for (int r = 0; r < 4; ++r) a[r] = As[tr*4+r][qq];
      #pragma unroll
      for (int c = 0; c < 8; ++c) {
        float lv = Ls[tc*8+c][qq];
        #pragma unroll
        for (int r = 0; r < 4; ++r) acc[r][c] += a[r] * lv;
      }
    }
    __syncthreads();
  }
  #pragma unroll
  for (int r = 0; r < 4; ++r) {
    #pragma unroll
    for (int c0 = 0; c0 < 8; c0 += 4) {
      float4 o = make_float4(acc[r][c0], acc[r][c0+1], acc[r][c0+2], acc[r][c0+3]);
      *(float4*)(P + pb + (size_t)(r0 + tr*4 + r) * NIND + jb + tc*8 + c0) = o;
    }
  }
}

// K6: trailing update A22 -= L21 L21^T
__global__ __launch_bounds__(256) void syrk_kernel(float* __restrict__ P, int it)
{
  __shared__ float Pa[64][17];
  __shared__ float Pb[64][17];
  int p = blockIdx.x;
  int a = (int)((sqrtf(8.f * p + 1.f) - 1.f) * 0.5f);
  while ((a + 1) * (a + 2) / 2 <= p) ++a;
  while (a * (a + 1) / 2 > p) --a;
  int b = p - a * (a + 1) / 2;
  const int tbase = (it + 1) * 2;
  const int r0 = (tbase + a) * 64, c0 = (tbase + b) * 64;
  const int jb = it * 128;
  const int k = blockIdx.y;
  const size_t pb = (size_t)k * NIND * NIND;
  const int tid = threadIdx.x, tr = tid >> 4, tc = tid & 15;
  float acc[4][4] = {};
  for (int j0 = 0; j0 < 128; j0 += 16) {
    int rr = tid >> 2, jj = (tid & 3) << 2;
    float4 v = *(const float4*)(P + pb + (size_t)(r0 + rr) * NIND + jb + j0 + jj);
    Pa[rr][jj] = v.x; Pa[rr][jj+1] = v.y; Pa[rr][jj+2] = v.z; Pa[rr][jj+3] = v.w;
    float4 u = *(const float4*)(P + pb + (size_t)(c0 + rr) * NIND + jb + j0 + jj);
    Pb[rr][jj] = u.x; Pb[rr][jj+1] = u.y; Pb[rr][jj+2] = u.z; Pb[rr][jj+3] = u.w;
    __syncthreads();
    #pragma unroll
    for (int qq = 0; qq < 16; ++qq) {
      float av[4], bv[4];
      #pragma unroll
      for (int r = 0; r < 4; ++r) av[r] = Pa[tr*4+r][qq];
      #pragma unroll
      for (int c = 0; c < 4; ++c) bv[c] = Pb[tc*4+c][qq];
      #pragma unroll
      for (int r = 0; r < 4; ++r)
        #pragma unroll
        for (int c = 0; c < 4; ++c) acc[r][c] += av[r] * bv[c];
    }
    __syncthreads();
  }
  #pragma unroll
  for (int r = 0; r < 4; ++r) {
    float* dst = P + pb + (size_t)(r0 + tr*4 + r) * NIND + c0 + tc*4;
    float4 cur = *(float4*)dst;
    cur.x -= acc[r][0]; cur.y -= acc[r][1]; cur.z -= acc[r][2]; cur.w -= acc[r][3];
    *(float4*)dst = cur;
  }
}

// K8 v2: generic 128x128-tile f32 GEMM for the doubling triangular inverse.
// mode 0: T1_p   = U(2p+1,2p+1) * L(2p+1,2p)                 -> Tsc   (grid 4,NCLS)
// mode 1: X1_p   = -T1_p * U(2p,2p)                          -> U     (grid 4,NCLS)
// mode 2: T2 r,c = Cinv256 * B256 tiles (q=bx>>2)            -> Tsc   (grid 8,NCLS)
// mode 3: X2 r,c = -T2 * Ainv256                             -> U     (grid 8,NCLS)
// mode 4: T3 r,c = Cinv512 * B512 tiles                      -> Tsc   (grid 16,NCLS)
// mode 5: X3 r,c = -T3 * Ainv512                             -> U     (grid 16,NCLS)
__global__ __launch_bounds__(256) void dgemm_kernel(
    const float* __restrict__ P, const float* __restrict__ Uin,
    float* __restrict__ Uf32, u16* __restrict__ Ubf16,
    float* __restrict__ Tsc, int mode)
{
  const int k = blockIdx.y;
  const int bx = blockIdx.x;
  const size_t ub = (size_t)k * NIND * NIND;
  const float* A = nullptr; const float* B = nullptr;
  float* Cf = nullptr; u16* Cb = nullptr; float* Ct = nullptr;
  int lda = 0, ldb = 0, ldc = 0, ldt = 0, K = 0;
  bool toU = false;
  if (mode == 0) {
    int p = bx;
    A = Uin + ub + (size_t)((2*p+1)*128) * NIND + (2*p+1)*128; lda = NIND;
    B = P + ub + (size_t)((2*p+1)*128) * NIND + (2*p)*128; ldb = NIND;
    Ct = Tsc + ((size_t)k*4 + p) * 16384; ldt = 128; K = 128;
  } else if (mode == 1) {
    int p = bx;
    A = Tsc + ((size_t)k*4 + p) * 16384; lda = 128;
    B = Uin + ub + (size_t)((2*p)*128) * NIND + (2*p)*128; ldb = NIND;
    Cf = Uf32 + ub + (size_t)((2*p+1)*128) * NIND + (2*p)*128;
    Cb = Ubf16 + ub + (size_t)((2*p+1)*128) * NIND + (2*p)*128;
    ldc = NIND; K = 128; toU = true;
  } else if (mode == 2) {
    int q = bx >> 2, r = (bx >> 1) & 1, c = bx & 1;
    A = Uin + ub + (size_t)((4*q+2+r)*128) * NIND + (4*q+2)*128; lda = NIND;
    B = P + ub + (size_t)((4*q+2)*128) * NIND + (4*q+c)*128; ldb = NIND;
    Ct = Tsc + ((size_t)k*2 + q) * 65536 + (size_t)r*128*256 + c*128; ldt = 256; K = 256;
  } else if (mode == 3) {
    int q = bx >> 2, r = (bx >> 1) & 1, c = bx & 1;
    A = Tsc + ((size_t)k*2 + q) * 65536 + (size_t)r*128*256; lda = 256;
    B = Uin + ub + (size_t)((4*q)*128) * NIND + (4*q)*128; ldb = NIND;
    Cf = Uf32 + ub + (size_t)((4*q+2+r)*128) * NIND + (4*q+c)*128;
    Cb = Ubf16 + ub + (size_t)((4*q+2+r)*128) * NIND + (4*q+c)*128;
    ldc = NIND; K = 256; toU = true;
  } else if (mode == 4) {
    int r = bx >> 2, c = bx & 3;
    A = Uin + ub + (size_t)((4+r)*128) * NIND + 512; lda = NIND;
    B = P + ub + (size_t)512 * NIND + c*128; ldb = NIND;
    Ct = Tsc + (size_t)k * 262144 + (size_t)r*128*512 + c*128; ldt = 512; K = 512;
  } else {
    int r = bx >> 2, c = bx & 3;
    A = Tsc + (size_t)k * 262144 + (size_t)r*128*512; lda = 512;
    B = Uin + ub + c*128; ldb = NIND;
    Cf = Uf32 + ub + (size_t)((4+r)*128) * NIND + c*128;
    Cb = Ubf16 + ub + (size_t)((4+r)*128) * NIND + c*128;
    ldc = NIND; K = 512; toU = true;
  }
  __shared__ float As[128][17];
  __shared__ float Bs[16][132];
  const int tid = threadIdx.x, tr = tid >> 4, tc = tid & 15;
  float acc[8][8] = {};
  for (int kb = 0; kb < K; kb += 16) {
    #pragma unroll
    for (int t = 0; t < 2; ++t) {
      int f = t * 256 + tid;
      int r2 = f >> 2, q4 = (f & 3) << 2;
      *(float4*)(&As[r2][q4]) = *(const float4*)(A + (size_t)r2 * lda + kb + q4);
    }
    #pragma unroll
    for (int t = 0; t < 2; ++t) {
      int f = t * 256 + tid;
      int q2 = f >> 5, c4 = (f & 31) << 2;
      *(float4*)(&Bs[q2][c4]) = *(const float4*)(B + (size_t)(kb + q2) * ldb + c4);
    }
    __syncthreads();
    #pragma unroll
    for (int q = 0; q < 16; ++q) {
      float a[8], b[8];
      #pragma unroll
      for (int r = 0; r < 8; ++r) a[r] = As[tr*8+r][q];
      #pragma unroll
      for (int c = 0; c < 8; ++c) b[c] = Bs[q][tc*8+c];
      #pragma unroll
      for (int r = 0; r < 8; ++r)
        #pragma unroll
        for (int c = 0; c < 8; ++c) acc[r][c] += a[r] * b[c];
    }
    __syncthreads();
  }
  if (toU) {
    #pragma unroll
    for (int r = 0; r < 8; ++r) {
      #pragma unroll
      for (int c = 0; c < 8; ++c) {
        float v = -acc[r][c];
        size_t idx = (size_t)(tr*8+r) * ldc + tc*8+c;
        Cf[idx] = v;
        Cb[idx] = (u16)f2bf(v);
      }
    }
  } else {
    #pragma unroll
    for (int r = 0; r < 8; ++r) {
      #pragma unroll
      for (int c = 0; c < 8; c += 4) {
        float4 o = make_float4(acc[r][c], acc[r][c+1], acc[r][c+2], acc[r][c+3]);
        *(float4*)(Ct + (size_t)(tr*8+r) * ldt + tc*8+c) = o;
      }
    }
  }
}

// K9: Y = U * phi^T (triangular K-limit), fused column square-sums -> partial[It][k][b]
__global__ __launch_bounds__(256) void ygemm_kernel(
    const u16* __restrict__ Ubf16, const u16* __restrict__ phiB,
    float* __restrict__ partial)
{
  __shared__ u16 Als[128 * 64];
  __shared__ u16 Bls[128 * 64];
  __shared__ float sq_lds[128][9];
  const int b0 = blockIdx.x * 128;
  const int It = blockIdx.y;
  const int k = blockIdx.z;
  const int tid = threadIdx.x;
  const int wid = tid >> 6, lane = tid & 63;
  const int wr = wid >> 1, wc = wid & 1;
  const u16* Ag = Ubf16 + (size_t)k * NIND * NIND + (size_t)(It * 128) * NIND;
  const u16* Bg = phiB + (size_t)b0 * NIND;
  f32x4 acc[4][4];
  #pragma unroll
  for (int m = 0; m < 4; ++m)
    #pragma unroll
    for (int n = 0; n < 4; ++n) acc[m][n] = (f32x4){0.f, 0.f, 0.f, 0.f};
  const int Kmax = (It + 1) * 128;
  for (int j0 = 0; j0 < Kmax; j0 += 64) {
    #pragma unroll
    for (int c = 0; c < 4; ++c) {
      int f = c * 256 + tid;
      int row = f >> 3, kc8 = f & 7;
      uint4 va = *(const uint4*)(Ag + (size_t)row * NIND + j0 + kc8 * 8);
      uint4 vb = *(const uint4*)(Bg + (size_t)row * NIND + j0 + kc8 * 8);
      int idx = (row * 64 + kc8 * 8) ^ ((row & 7) << 3);
      *(uint4*)(&Als[idx]) = va;
      *(uint4*)(&Bls[idx]) = vb;
    }
    __syncthreads();
    #pragma unroll
    for (int ks = 0; ks < 2; ++ks) {
      bf16x8 af[4], bfr[4];
      #pragma unroll
      for (int m = 0; m < 4; ++m) {
        int row = wr * 64 + m * 16 + (lane & 15);
        int kb = ks * 32 + (lane >> 4) * 8;
        int idx = (row * 64 + kb) ^ ((row & 7) << 3);
        af[m] = *(const bf16x8*)(&Als[idx]);
      }
      #pragma unroll
      for (int n = 0; n < 4; ++n) {
        int row = wc * 64 + n * 16 + (lane & 15);
        int kb = ks * 32 + (lane >> 4) * 8;
        int idx = (row * 64 + kb) ^ ((row & 7) << 3);
        bfr[n] = *(const bf16x8*)(&Bls[idx]);
      }
      #pragma unroll
      for (int m = 0; m < 4; ++m)
        #pragma unroll
        for (int n = 0; n < 4; ++n)
          acc[m][n] = __builtin_amdgcn_mfma_f32_16x16x32_bf16(af[m], bfr[n], acc[m][n], 0, 0, 0);
    }
    __syncthreads();
  }
  #pragma unroll
  for (int n = 0; n < 4; ++n) {
    float s = 0.f;
    #pragma unroll
    for (int m = 0; m < 4; ++m)
      #pragma unroll
      for (int r = 0; r < 4; ++r) { float v = acc[m][n][r]; s += v * v; }
    int col = wc * 64 + n * 16 + (lane & 15);
    sq_lds[col][wr * 4 + (lane >> 4)] = s;
  }
  __syncthreads();
  if (tid < 128) {
    float s = 0.f;
    #pragma unroll
    for (int t = 0; t < 8; ++t) s += sq_lds[tid][t];
    partial[((size_t)It * NCLS + k) * BATCH + b0 + tid] = s;
  }
}

// K10: out variances[b][k] = sum_It partial[It][k][b]
__global__ __launch_bounds__(256) void reduce_kernel(
    const float* __restrict__ partial, float* __restrict__ out)
{
  int t = blockIdx.x * 256 + threadIdx.x;
  int k = t >> 11, b = t & 2047;
  float s = 0.f;
  #pragma unroll
  for (int It = 0; It < 8; ++It)
    s += partial[((size_t)It * NCLS + k) * BATCH + b];
  out[(size_t)BATCH * NCLS + (size_t)b * NCLS + k] = s;
}

extern "C" void kernel_launch(void* const* d_in, const int* in_sizes, int n_in,
                              void* d_out, int out_size, void* d_ws, size_t ws_size,
                              hipStream_t stream)
{
  (void)in_sizes; (void)n_in; (void)ws_size;
  const float* x   = (const float*)d_in[0];
  const float* rw  = (const float*)d_in[1];
  const float* rb  = (const float*)d_in[2];
  const float* bw  = (const float*)d_in[3];
  const float* bb  = (const float*)d_in[4];
  const float* prc = (const float*)d_in[5];
  float* out = (float*)d_out;
  char* ws = (char*)d_ws;
  size_t off = 0;
  auto alloc = [&](size_t bytes) -> void* {
    void* p = ws + off;
    off = (off + bytes + 255) & ~(size_t)255;
    return p;
  };
  float* phi   = (float*)alloc((size_t)BATCH * NIND * 4);
  u16*   phiB  = (u16*)  alloc((size_t)BATCH * NIND * 2);
  float* phiT  = (float*)alloc((size_t)NIND * BATCH * 4);
  u16*   phiTB = (u16*)  alloc((size_t)NIND * BATCH * 2);
  float* wmat  = (float*)alloc((size_t)NCLS * BATCH * 4);
  float* P     = (float*)alloc((size_t)NCLS * NIND * NIND * 4);
  float* invL  = (float*)alloc((size_t)NCLS * 8 * 128 * 128 * 4);
  u16*   Ubf16 = (u16*)  alloc((size_t)NCLS * NIND * NIND * 2);
  float* partial = (float*)alloc((size_t)8 * NCLS * BATCH * 4);
  // union: phiW (bf16, 64MB, dead after gram) aliased with Uf32 (f32, 64MB)
  u16*   phiW = (u16*)(ws + off);
  float* Uf32 = (float*)(ws + off);
  float* Tsc  = (float*)(ws + off + (size_t)NCLS * NIND * NIND * 4);  // 16MB scratch

  hipMemsetAsync(d_out, 0, (size_t)out_size * sizeof(float), stream);
  phi_kernel<<<dim3(BATCH/64, NIND/64), 256, 0, stream>>>(x, rw, rb, phi, phiB, phiT, phiTB);
  logits_kernel<<<dim3(BATCH/64), 256, 0, stream>>>(phi, bw, bb, out, wmat);
  scalew_kernel<<<dim3(1024, NCLS), 256, 0, stream>>>(phiT, wmat, phiW);
  gram_kernel<<<dim3(36, NCLS), 256, 0, stream>>>(phiW, phiTB, prc, P);
  // zero U (esp. strictly-upper blocks read as zeros by the doubling GEMMs);
  // phiW is dead from here on, so the alias is safe in stream order.
  hipMemsetAsync(Uf32, 0, (size_t)NCLS * NIND * NIND * 4, stream);
  for (int it = 0; it < 8; ++it) {
    potrf_kernel<<<dim3(NCLS), 1024, 0, stream>>>(P, invL, Uf32, Ubf16, it);
    if (it < 7) {
      trsm_kernel<<<dim3((7 - it) * 2, NCLS), 256, 0, stream>>>(P, invL, it);
      int n = 14 - 2 * it;
      syrk_kernel<<<dim3(n * (n + 1) / 2, NCLS), 256, 0, stream>>>(P, it);
    }
  }
  // binary-doubling triangular inverse: 128 -> 256 -> 512 -> 1024
  dgemm_kernel<<<dim3(4,  NCLS), 256, 0, stream>>>(P, Uf32, Uf32, Ubf16, Tsc, 0);
  dgemm_kernel<<<dim3(4,  NCLS), 256, 0, stream>>>(P, Uf32, Uf32, Ubf16, Tsc, 1);
  dgemm_kernel<<<dim3(8,  NCLS), 256, 0, stream>>>(P, Uf32, Uf32, Ubf16, Tsc, 2);
  dgemm_kernel<<<dim3(8,  NCLS), 256, 0, stream>>>(P, Uf32, Uf32, Ubf16, Tsc, 3);
  dgemm_kernel<<<dim3(16, NCLS), 256, 0, stream>>>(P, Uf32, Uf32, Ubf16, Tsc, 4);
  dgemm_kernel<<<dim3(16, NCLS), 256, 0, stream>>>(P, Uf32, Uf32, Ubf16, Tsc, 5);
  ygemm_kernel<<<dim3(BATCH/128, 8, NCLS), 256, 0, stream>>>(Ubf16, phiB, partial);
  reduce_kernel<<<dim3(128), 256, 0, stream>>>(partial, out);
}